// Round 8
// baseline (98.901 us; speedup 1.0000x reference)
//
#include <hip/hip_runtime.h>

#define TILE 256

typedef float f32x4 __attribute__((ext_vector_type(4)));

__global__ __launch_bounds__(256) void returning_rate_kernel(
    const float* __restrict__ pred, const float* __restrict__ mask,
    float* __restrict__ out, int B) {
  __shared__ float o1s[TILE * 5];
  __shared__ float o2s[TILE * 5];

  const int t = threadIdx.x;
  const long long blockRow = (long long)blockIdx.x * TILE;
  const long long s = blockRow + t;
  const int nrows = (int)((blockRow + TILE <= (long long)B) ? TILE : ((long long)B - blockRow));

  if (t < nrows) {
    const float* pr = pred + s * 25;
    const float* mk = mask + s * 25;

    // pred: normal (allocating) loads -> pred's 200MB stays L3-resident.
    float p40 = pr[20], p41 = pr[21], p42 = pr[22], p43 = pr[23], p44 = pr[24];
    float p31 = pr[16], p32 = pr[17], p33 = pr[18], p34 = pr[19];
    float p22 = pr[12], p23 = pr[13], p24 = pr[14];
    float p13 = pr[8],  p14 = pr[9];
    float p04 = pr[4];
    // mask: non-temporal (streaming) loads -> don't displace pred in L3.
    float m04 = __builtin_nontemporal_load(mk + 4);
    float m13 = __builtin_nontemporal_load(mk + 8);
    float m22 = __builtin_nontemporal_load(mk + 12);
    float m31 = __builtin_nontemporal_load(mk + 16);

    // p1: mask multiplies only the LAST product term (Python precedence)
    float p1_1 = p40 * p41 * m31;
    float p1_2 = p40 * p42 + p31 * p32 * m22;
    float p1_3 = p40 * p43 + p31 * p33 + p22 * p23 * m13;
    float p1_4 = p40 * p44 + p31 * p34 + p22 * p24 + p13 * p14 * m04;

    float q40 = 1.f - p40, q31 = 1.f - p31, q22 = 1.f - p22, q13 = 1.f - p13;
    float p2_1 = q31 * (1.f - q40) * m31;
    float p2_2 = q22 * (1.f - q40 * q31) * m22;
    float p2_3 = q13 * (1.f - q40 * q31 * q22) * m13;
    float p2_4 = (1.f - p04) * (1.f - q40 * q31 * q22 * q13) * m04;

    float* a = o1s + t * 5;   // stride 5 -> 2 lanes/bank, free
    a[0] = 0.f; a[1] = p1_1; a[2] = p1_2; a[3] = p1_3; a[4] = p1_4;
    float* b = o2s + t * 5;
    b[0] = 0.f; b[1] = p2_1; b[2] = p2_2; b[3] = p2_3; b[4] = p2_4;
  }
  __syncthreads();

  // Full-line non-temporal float4 stores (proven: WRITE_SIZE == exact 80MB).
  const int nfloats = nrows * 5;
  const int nv4 = nfloats / 4;
  float* g1 = out + blockRow * 5;                      // 5120*bid B -> 16B aligned
  float* g2 = out + (long long)B * 5 + blockRow * 5;   // B*20 B divisible by 16

  for (int i = t; i < nv4; i += 256) {
    f32x4 v1, v2;
    __builtin_memcpy(&v1, &o1s[i * 4], 16);
    __builtin_memcpy(&v2, &o2s[i * 4], 16);
    __builtin_nontemporal_store(v1, (f32x4*)g1 + i);
    __builtin_nontemporal_store(v2, (f32x4*)g2 + i);
  }
  for (int i = nv4 * 4 + t; i < nfloats; i += 256) {
    g1[i] = o1s[i];
    g2[i] = o2s[i];
  }
}

extern "C" void kernel_launch(void* const* d_in, const int* in_sizes, int n_in,
                              void* d_out, int out_size, void* d_ws, size_t ws_size,
                              hipStream_t stream) {
  const float* pred = (const float*)d_in[0];
  const float* mask = (const float*)d_in[1];
  float* out = (float*)d_out;
  int B = in_sizes[0] / 25;

  int blocks = (int)(((long long)B + TILE - 1) / TILE);
  returning_rate_kernel<<<blocks, 256, 0, stream>>>(pred, mask, out, B);
}

// Round 9
// 88.316 us; speedup vs baseline: 1.1199x; 1.1199x over previous
//
#include <hip/hip_runtime.h>

#define TILE 256

typedef float f32x4 __attribute__((ext_vector_type(4)));

__global__ __launch_bounds__(256) void returning_rate_kernel(
    const float* __restrict__ pred, const float* __restrict__ mask,
    float* __restrict__ out, int B) {
  __shared__ float o1s[TILE * 5];
  __shared__ float o2s[TILE * 5];

  const int t = threadIdx.x;
  const long long blockRow = (long long)blockIdx.x * TILE;
  const long long s = blockRow + t;
  const int nrows = (int)((blockRow + TILE <= (long long)B) ? TILE : ((long long)B - blockRow));

  if (t < nrows) {
    const float* pr = pred + s * 25;
    const float* mk = mask + s * 25;

    // Scalar input loads (R1/R6-proven; address divergence is NOT the limiter
    // — R7's fully-coalesced async staging ties this at ~88 us).
    float p40 = pr[20], p41 = pr[21], p42 = pr[22], p43 = pr[23], p44 = pr[24];
    float p31 = pr[16], p32 = pr[17], p33 = pr[18], p34 = pr[19];
    float p22 = pr[12], p23 = pr[13], p24 = pr[14];
    float p13 = pr[8],  p14 = pr[9];
    float p04 = pr[4];
    float m31 = mk[16], m22 = mk[12], m13 = mk[8], m04 = mk[4];

    // p1: mask multiplies only the LAST product term (Python precedence)
    float p1_1 = p40 * p41 * m31;
    float p1_2 = p40 * p42 + p31 * p32 * m22;
    float p1_3 = p40 * p43 + p31 * p33 + p22 * p23 * m13;
    float p1_4 = p40 * p44 + p31 * p34 + p22 * p24 + p13 * p14 * m04;

    float q40 = 1.f - p40, q31 = 1.f - p31, q22 = 1.f - p22, q13 = 1.f - p13;
    float p2_1 = q31 * (1.f - q40) * m31;
    float p2_2 = q22 * (1.f - q40 * q31) * m22;
    float p2_3 = q13 * (1.f - q40 * q31 * q22) * m13;
    float p2_4 = (1.f - p04) * (1.f - q40 * q31 * q22 * q13) * m04;

    float* a = o1s + t * 5;   // stride 5 -> gcd(5,32)=1 -> 2 lanes/bank, free
    a[0] = 0.f; a[1] = p1_1; a[2] = p1_2; a[3] = p1_3; a[4] = p1_4;
    float* b = o2s + t * 5;
    b[0] = 0.f; b[1] = p2_1; b[2] = p2_2; b[3] = p2_3; b[4] = p2_4;
  }
  __syncthreads();

  // Full-line non-temporal float4 stores (proven: WRITE_SIZE == exact 80MB,
  // best dur; keeps dead output writes from churning L3).
  const int nfloats = nrows * 5;
  const int nv4 = nfloats / 4;
  float* g1 = out + blockRow * 5;                      // 5120*bid B -> 16B aligned
  float* g2 = out + (long long)B * 5 + blockRow * 5;   // B*20 B divisible by 16

  for (int i = t; i < nv4; i += 256) {
    f32x4 v1, v2;
    __builtin_memcpy(&v1, &o1s[i * 4], 16);
    __builtin_memcpy(&v2, &o2s[i * 4], 16);
    __builtin_nontemporal_store(v1, (f32x4*)g1 + i);
    __builtin_nontemporal_store(v2, (f32x4*)g2 + i);
  }
  for (int i = nv4 * 4 + t; i < nfloats; i += 256) {
    g1[i] = o1s[i];
    g2[i] = o2s[i];
  }
}

extern "C" void kernel_launch(void* const* d_in, const int* in_sizes, int n_in,
                              void* d_out, int out_size, void* d_ws, size_t ws_size,
                              hipStream_t stream) {
  const float* pred = (const float*)d_in[0];
  const float* mask = (const float*)d_in[1];
  float* out = (float*)d_out;
  int B = in_sizes[0] / 25;

  int blocks = (int)(((long long)B + TILE - 1) / TILE);
  returning_rate_kernel<<<blocks, 256, 0, stream>>>(pred, mask, out, B);
}